// Round 17
// baseline (1143.012 us; speedup 1.0000x reference)
//
#include <hip/hip_runtime.h>

constexpr int B_   = 64;
constexpr int P_   = 49;
constexpr int T_   = 20;
constexpr int V_   = 32000;
constexpr int E_   = 512;
constexpr int D_   = 512;
constexpr int A_   = 512;
constexpr int ENC_ = 2048;
constexpr int NT_  = T_ - 1;
constexpr int KX_  = ENC_ + E_ + D_;   // 3072
constexpr int KSPL = 8;                // gates split-K (R6-proven)

#define DI __device__ __forceinline__

using u16 = unsigned short;
typedef short   bf16x8 __attribute__((ext_vector_type(8)));
typedef float   f32x4  __attribute__((ext_vector_type(4)));
typedef u16     u16x4  __attribute__((ext_vector_type(4)));
typedef u16     u16x2  __attribute__((ext_vector_type(2)));

DI float sigm(float x) { return 1.0f / (1.0f + __expf(-x)); }
DI float tanhx(float x) {
  x = fminf(15.0f, fmaxf(-15.0f, x));
  float e = __expf(2.0f * x);
  return (e - 1.0f) / (e + 1.0f);
}
DI u16 f2bf(float x) {
  union { float f; unsigned u; } v{x};
  unsigned r = v.u + 0x7FFF + ((v.u >> 16) & 1);   // RNE
  return (u16)(r >> 16);
}
DI float bf2f(u16 x) {
  union { unsigned u; float f; } v;
  v.u = ((unsigned)x) << 16;
  return v.f;
}
DI f32x4 mfma16(bf16x8 a, bf16x8 b, f32x4 c) {
  return __builtin_amdgcn_mfma_f32_16x16x32_bf16(a, b, c, 0, 0, 0);
}

// ========== P1-small: fused light converters (uniform 4.2KB smem) ==========
constexpr int PRO1_BLOCKS = 16256;

DI void dev_tr_cvt(const float* in, u16* outp, int R, int C, int bx, int by,
                   float (*tbuf)[33]) {
  int tx = threadIdx.x & 31, ty = threadIdx.x >> 5;
  int c0 = bx * 32, r0 = by * 32;
#pragma unroll
  for (int i = 0; i < 4; i++)
    tbuf[ty + 8 * i][tx] = in[(size_t)(r0 + ty + 8 * i) * C + c0 + tx];
  __syncthreads();
#pragma unroll
  for (int i = 0; i < 4; i++)
    outp[(size_t)(c0 + ty + 8 * i) * R + r0 + tx] = f2bf(tbuf[tx][ty + 8 * i]);
}

__global__ __launch_bounds__(256) void k_pro1s(
    const float* __restrict__ feat, const float* __restrict__ Winh,
    const float* __restrict__ Winc, const float* __restrict__ Wenc,
    const float* __restrict__ Wdec, const float* __restrict__ Wih,
    const float* __restrict__ Whh, u16* __restrict__ mfb,
    u16* __restrict__ featb, u16* __restrict__ WiT, u16* __restrict__ WeT,
    u16* __restrict__ WdT, u16* __restrict__ Wg) {
  __shared__ float tbuf[32][33];
  int bid = blockIdx.x;
  if (bid < 6272) {                       // cvt4 feat
    int i = bid * 256 + threadIdx.x;
    float4 v = ((const float4*)feat)[i];
    u16x4 r = {f2bf(v.x), f2bf(v.y), f2bf(v.z), f2bf(v.w)};
    ((u16x4*)featb)[i] = r;
  } else if (bid < 6784) {                // mean
    int idx = (bid - 6272) * 256 + threadIdx.x;
    int b = idx >> 11, e = idx & (ENC_ - 1);
    const float* f = feat + (size_t)b * P_ * ENC_ + e;
    float s = 0.f;
#pragma unroll
    for (int p = 0; p < P_; p++) s += f[(size_t)p * ENC_];
    mfb[idx] = f2bf(s * (1.0f / P_));
  } else if (bid < 7808) {                // tr Winh
    int l = bid - 6784;
    dev_tr_cvt(Winh, WiT, ENC_, D_, l & 15, l >> 4, tbuf);
  } else if (bid < 8832) {                // tr Winc
    int l = bid - 7808;
    dev_tr_cvt(Winc, WiT + (size_t)D_ * ENC_, ENC_, D_, l & 15, l >> 4, tbuf);
  } else if (bid < 9856) {                // tr Wenc
    int l = bid - 8832;
    dev_tr_cvt(Wenc, WeT, ENC_, A_, l & 15, l >> 4, tbuf);
  } else if (bid < 10112) {               // tr Wdec
    int l = bid - 9856;
    dev_tr_cvt(Wdec, WdT, D_, A_, l & 15, l >> 4, tbuf);
  } else {                                // wg4
    int i = (bid - 10112) * 256 + threadIdx.x;
    int j = i / 768, rem = i - j * 768;
    int k = rem * 4;
    const float* src = (k < ENC_ + E_) ? (Wih + (size_t)j * (ENC_ + E_) + k)
                                       : (Whh + (size_t)j * D_ + (k - ENC_ - E_));
    float4 v = *(const float4*)src;
    u16x4 r = {f2bf(v.x), f2bf(v.y), f2bf(v.z), f2bf(v.w)};
    ((u16x4*)Wg)[i] = r;
  }
}

// Wout transpose: f32 [512][32000] -> bf16 [32000][512]; 512B-contiguous
__global__ __launch_bounds__(256) void k_trW(const float* __restrict__ in,
                                             u16* __restrict__ outp) {
  __shared__ u16 ld[128][264];
  int v0 = blockIdx.x * 128, k0 = blockIdx.y * 256;
  int vf = (threadIdx.x & 31) * 4, kk = threadIdx.x >> 5;
#pragma unroll 4
  for (int p = 0; p < 32; p++) {
    int k = kk + p * 8;
    float4 v = *(const float4*)(in + (size_t)(k0 + k) * V_ + v0 + vf);
    ld[vf + 0][k] = f2bf(v.x);
    ld[vf + 1][k] = f2bf(v.y);
    ld[vf + 2][k] = f2bf(v.z);
    ld[vf + 3][k] = f2bf(v.w);
  }
  __syncthreads();
  int v = threadIdx.x >> 1, h = threadIdx.x & 1;
  u16* op = outp + (size_t)(v0 + v) * D_ + k0 + h * 128;
#pragma unroll
  for (int i = 0; i < 16; i++)
    *(bf16x8*)(op + i * 8) = *(const bf16x8*)(&ld[v][h * 128 + i * 8]);
}

// ========== P2: init_bf (16 blocks; h0 -> hall[0]) + enc_bf (392) =========

__global__ __launch_bounds__(256) void k_pro2(const u16* __restrict__ mfb,
    const u16* __restrict__ WiT, const float* __restrict__ binh,
    const float* __restrict__ binc, u16* __restrict__ hall0,
    float* __restrict__ c, const u16* __restrict__ featb,
    const u16* __restrict__ WeT, const float* __restrict__ benc,
    float* __restrict__ encs) {
  int wid = threadIdx.x >> 6, lane = threadIdx.x & 63;
  int l16 = lane & 15, lk = lane >> 4;
  if (blockIdx.x < 16) {   // init: h0|c0 = mfb @ WiT
    int n0 = blockIdx.x * 64 + wid * 16;
    const u16* bp = WiT + (size_t)(n0 + l16) * ENC_ + 8 * lk;
    const u16* ap = mfb + (size_t)l16 * ENC_ + 8 * lk;
    f32x4 acc[4] = {};
#pragma unroll 4
    for (int kc = 0; kc < ENC_; kc += 32) {
      bf16x8 b = *(const bf16x8*)(bp + kc);
#pragma unroll
      for (int mf = 0; mf < 4; mf++) {
        bf16x8 a = *(const bf16x8*)(ap + (size_t)mf * 16 * ENC_ + kc);
        acc[mf] = mfma16(a, b, acc[mf]);
      }
    }
    int n = n0 + l16;
#pragma unroll
    for (int mf = 0; mf < 4; mf++) {
      int m = mf * 16 + 4 * lk;
#pragma unroll
      for (int r = 0; r < 4; r++) {
        float v = acc[mf][r];
        if (n < D_) hall0[(size_t)(m + r) * D_ + n] = f2bf(v + binh[n]);
        else        c[(size_t)(m + r) * D_ + (n - D_)] = v + binc[n - D_];
      }
    }
  } else {                 // enc_states GEMM
    int l = blockIdx.x - 16;
    int m0 = (l % 49) * 64, n0 = (l / 49) * 64 + wid * 16;
    const u16* ap = featb + (size_t)(m0 + l16) * ENC_ + 8 * lk;
    const u16* bp = WeT + (size_t)(n0 + l16) * ENC_ + 8 * lk;
    f32x4 acc[4] = {};
#pragma unroll 8
    for (int i = 0; i < ENC_ / 32; i++) {
      int kc = i * 32;
      bf16x8 b = *(const bf16x8*)(bp + kc);
#pragma unroll
      for (int mf = 0; mf < 4; mf++) {
        bf16x8 a = *(const bf16x8*)(ap + (size_t)mf * 16 * ENC_ + kc);
        acc[mf] = mfma16(a, b, acc[mf]);
      }
    }
    float bv = benc[n0 + l16];
#pragma unroll
    for (int mf = 0; mf < 4; mf++) {
      int m = m0 + mf * 16 + 4 * lk;
#pragma unroll
      for (int r = 0; r < 4; r++)
        encs[(size_t)(m + r) * A_ + n0 + l16] = acc[mf][r] + bv;
    }
  }
}

// ====== loop: k_att3 (R6-proven grid (64,2)) + k_gates_bf (32,8) ==========

__global__ __launch_bounds__(512) void k_att3(const u16* __restrict__ featb,
    const float* __restrict__ encs, const u16* __restrict__ WdT,
    const float* __restrict__ bdec, const float* __restrict__ wA,
    const float* __restrict__ bA, const float* __restrict__ gp,
    const float* __restrict__ bih, const float* __restrict__ bhh,
    const float* __restrict__ c_in, float* __restrict__ c_out,
    u16* __restrict__ hcur, u16* __restrict__ ctxb,
    const int* __restrict__ cap, const float* __restrict__ tab,
    u16* __restrict__ embt, int t, int do_reduce, int do_att) {
  __shared__ u16 hsb[D_];
  __shared__ float ds[A_];
  __shared__ float sc[P_];
  __shared__ float inv_s;
  int b = blockIdx.x, y = blockIdx.y, tid = threadIdx.x;

  if (do_att && y == 0) {   // emb gather for THIS step
    int tok = cap[b * T_ + t];
    embt[(size_t)b * E_ + tid] = f2bf(tab[(size_t)tok * E_ + tid]);
  }

  if (do_reduce) {
    int d = tid;
    float g0 = 0, g1 = 0, g2 = 0, g3 = 0;
#pragma unroll
    for (int s = 0; s < KSPL; s++) {
      const float* g = gp + (size_t)(s * B_ + b) * (4 * D_);
      g0 += g[d]; g1 += g[D_ + d]; g2 += g[2 * D_ + d]; g3 += g[3 * D_ + d];
    }
    g0 += bih[d] + bhh[d];
    g1 += bih[D_ + d] + bhh[D_ + d];
    g2 += bih[2 * D_ + d] + bhh[2 * D_ + d];
    g3 += bih[3 * D_ + d] + bhh[3 * D_ + d];
    float iv = sigm(g0), fv = sigm(g1), gv = tanhx(g2), ov = sigm(g3);
    float cv = fmaf(fv, c_in[b * D_ + d], iv * gv);
    float hv = ov * tanhx(cv);
    u16 hb = f2bf(hv);
    hsb[d] = hb;
    if (y == 0) {
      c_out[b * D_ + d] = cv;
      hcur[b * D_ + d] = hb;
    }
  } else {
    hsb[tid] = hcur[b * D_ + tid];
  }
  __syncthreads();
  if (!do_att) return;

  // dec = h @ Wdec + bdec (broadcast-row MFMA)
  {
    int w = tid >> 6, lane = tid & 63, l16 = lane & 15, lk = lane >> 4;
#pragma unroll
    for (int f = 0; f < 4; f++) {
      int n = w * 64 + f * 16 + l16;
      const u16* bp = WdT + (size_t)n * D_ + 8 * lk;
      f32x4 acc = {};
#pragma unroll
      for (int kc = 0; kc < D_; kc += 32) {
        bf16x8 av = *(const bf16x8*)(hsb + kc + 8 * lk);
        bf16x8 bv = *(const bf16x8*)(bp + kc);
        acc = mfma16(av, bv, acc);
      }
      if (lk == 0) ds[n] = acc[0] + bdec[n];
    }
  }
  __syncthreads();

  // scores
  {
    int wv_ = tid >> 6, ln = tid & 63;
    float bA0 = bA[0];
    for (int p = wv_; p < P_; p += 8) {
      const float* ep = encs + (size_t)(b * P_ + p) * A_;
      float s = 0.f;
#pragma unroll
      for (int a = ln; a < A_; a += 64) s += tanhx(ep[a] + ds[a]) * wA[a];
#pragma unroll
      for (int off = 32; off; off >>= 1) s += __shfl_down(s, off);
      if (ln == 0) sc[p] = s + bA0;
    }
  }
  __syncthreads();
  if (tid == 0) {
    float mx = -1e30f;
    for (int p = 0; p < P_; p++) mx = fmaxf(mx, sc[p]);
    float sum = 0.f;
    for (int p = 0; p < P_; p++) { float ex = __expf(sc[p] - mx); sc[p] = ex; sum += ex; }
    inv_s = 1.0f / sum;
  }
  __syncthreads();

  // ctx: u16x2 per thread, y-half of ENC (R6-proven)
  {
    float inv = inv_s;
    int e = y * 1024 + tid * 2;
    const u16* fp = featb + (size_t)b * P_ * ENC_ + e;
    float s0 = 0.f, s1 = 0.f;
#pragma unroll
    for (int p = 0; p < P_; p++) {
      u16x2 w = *(const u16x2*)(fp + (size_t)p * ENC_);
      s0 = fmaf(bf2f(w.x), sc[p], s0);
      s1 = fmaf(bf2f(w.y), sc[p], s1);
    }
    u16x2 o = {f2bf(s0 * inv), f2bf(s1 * inv)};
    *(u16x2*)(ctxb + b * ENC_ + e) = o;
  }
}

__global__ __launch_bounds__(256) void k_gates_bf(const u16* __restrict__ ctxb,
    const u16* __restrict__ embt, const u16* __restrict__ hcur,
    const u16* __restrict__ Wg, float* __restrict__ gp) {
  int wid = threadIdx.x >> 6, lane = threadIdx.x & 63;
  int j0 = blockIdx.x * 64 + wid * 16;
  int sp = blockIdx.y;
  int l16 = lane & 15, lk = lane >> 4;
  const u16* bp = Wg + (size_t)(j0 + l16) * KX_ + 8 * lk;
  f32x4 acc[4] = {};
#pragma unroll
  for (int i = 0; i < KX_ / KSPL / 32; i++) {   // 12 chunks
    int kc = sp * (KX_ / KSPL) + i * 32;
    int k = kc + 8 * lk;
    bf16x8 b = *(const bf16x8*)(bp + kc);
#pragma unroll
    for (int mf = 0; mf < 4; mf++) {
      int row = mf * 16 + l16;
      const u16* src;
      if (k < ENC_)            src = ctxb + (size_t)row * ENC_ + k;
      else if (k < ENC_ + E_)  src = embt + (size_t)row * E_ + (k - ENC_);
      else                     src = hcur + (size_t)row * D_ + (k - ENC_ - E_);
      bf16x8 a = *(const bf16x8*)src;
      acc[mf] = mfma16(a, b, acc[mf]);
    }
  }
#pragma unroll
  for (int mf = 0; mf < 4; mf++) {
    int m = mf * 16 + 4 * lk;
#pragma unroll
    for (int r = 0; r < 4; r++)
      gp[((size_t)sp * B_ + m + r) * (4 * D_) + j0 + l16] = acc[mf][r];
  }
}

// ====== batched logits v6: s-clustered block order (concurrent writes
// cover each output row contiguously), XCD-stable nt (grid.x=128 pad) ======

__global__ __launch_bounds__(256) void k_logits6(const u16* __restrict__ hall,
    const u16* __restrict__ WoT, const float* __restrict__ bout,
    float* __restrict__ out) {
  __shared__ float tile[64 * 264];
  int nt = blockIdx.x;          // 0..127; XCD = nt%8 stable across s
  int s  = blockIdx.y;          // 0..19
  if (nt >= 125) return;
  if (s == NT_) {   // t = T-1 zero-fill plane
    int tr = threadIdx.x >> 2, tc = threadIdx.x & 3;
    f32x4 z = {0.f, 0.f, 0.f, 0.f};
    float* op = out + ((size_t)tr * T_ + NT_) * V_ + nt * 256;
#pragma unroll
    for (int j = 0; j < 16; j++)
      __builtin_nontemporal_store(z, (f32x4*)(op + (tc + j * 4) * 4));
    return;
  }
  int w = threadIdx.x >> 6, lane = threadIdx.x & 63;
  int l16 = lane & 15, lk = lane >> 4;
  const u16* ap0 = hall + (size_t)s * B_ * D_ + (size_t)l16 * D_ + 8 * lk;
  int ncol0 = nt * 256 + w * 64;
#pragma unroll 1
  for (int ch = 0; ch < 4; ch++) {
    int col = ncol0 + ch * 16 + l16;
    const u16* bp = WoT + (size_t)col * D_ + 8 * lk;
    f32x4 acc[4] = {};
#pragma unroll
    for (int kc = 0; kc < 16; kc++) {
      bf16x8 b = *(const bf16x8*)(bp + kc * 32);
#pragma unroll
      for (int mf = 0; mf < 4; mf++) {
        bf16x8 a = *(const bf16x8*)(ap0 + (size_t)mf * 16 * D_ + kc * 32);
        acc[mf] = mfma16(a, b, acc[mf]);
      }
    }
    float bv = bout[col];
#pragma unroll
    for (int mf = 0; mf < 4; mf++)
#pragma unroll
      for (int rr = 0; rr < 4; rr++)
        tile[(mf * 16 + 4 * lk + rr) * 264 + w * 64 + ch * 16 + l16] =
            acc[mf][rr] + bv;
  }
  __syncthreads();
  int tr = threadIdx.x >> 2, tc = threadIdx.x & 3;
  float* op = out + ((size_t)tr * T_ + s) * V_ + nt * 256;
  const float* lp = &tile[tr * 264];
#pragma unroll
  for (int j = 0; j < 16; j++) {
    int cc = (tc + j * 4) * 4;
    __builtin_nontemporal_store(*(const f32x4*)(lp + cc), (f32x4*)(op + cc));
  }
}

// ================= fp32 fallback path (R0 kernels) =================

DI int swz(int row, int slot) { return row * 64 + ((slot ^ (row >> 2)) << 2); }

__global__ __launch_bounds__(256) void k_mean(const float* __restrict__ feat,
                                              float* __restrict__ mf) {
  int idx = blockIdx.x * 256 + threadIdx.x;
  int b = idx >> 11, e = idx & (ENC_ - 1);
  const float* f = feat + (size_t)b * P_ * ENC_ + e;
  float s = 0.f;
#pragma unroll
  for (int p = 0; p < P_; p++) s += f[(size_t)p * ENC_];
  mf[idx] = s * (1.0f / P_);
}

__global__ __launch_bounds__(256) void k_emb(const int* __restrict__ cap,
                                             const float* __restrict__ tab,
                                             float* __restrict__ emb) {
  int idx = blockIdx.x * 256 + threadIdx.x;
  int e  = idx & (E_ - 1);
  int bt = idx >> 9;
  int b = bt / NT_, t = bt - b * NT_;
  int tok = cap[b * T_ + t];
  emb[idx] = tab[(size_t)tok * E_ + e];
}

__global__ __launch_bounds__(256) void k_init(const float* __restrict__ mf,
    const float* __restrict__ Wh, const float* __restrict__ bh,
    const float* __restrict__ Wc, const float* __restrict__ bc,
    float* __restrict__ h, float* __restrict__ c) {
  __shared__ float ms[ENC_];
  int b = blockIdx.y;
  for (int i = threadIdx.x; i < ENC_; i += 256) ms[i] = mf[b * ENC_ + i];
  __syncthreads();
  int d = blockIdx.x * 256 + threadIdx.x;
  const float* W = blockIdx.z ? Wc : Wh;
  float s = (blockIdx.z ? bc : bh)[d];
#pragma unroll 8
  for (int e = 0; e < ENC_; e++) s = fmaf(ms[e], W[(size_t)e * D_ + d], s);
  (blockIdx.z ? c : h)[b * D_ + d] = s;
}

__global__ __launch_bounds__(256) void k_zero_last(float* __restrict__ out) {
  int i = blockIdx.x * 256 + threadIdx.x;
  int b = i / 8000, v4 = i - b * 8000;
  float4 z = {0.f, 0.f, 0.f, 0.f};
  *(float4*)(out + ((size_t)b * T_ + (T_ - 1)) * V_ + (size_t)v4 * 4) = z;
}

__global__ __launch_bounds__(256) void k_enc(const float* __restrict__ Ag,
    const float* __restrict__ Wg, const float* __restrict__ bias,
    float* __restrict__ Cg) {
  __shared__ float As[64 * 64], Ws[64 * 64];
  int m0 = blockIdx.x * 64, n0 = blockIdx.y * 64;
  int tid = threadIdx.x, tn = tid & 15, tm = tid >> 4;
  float acc[4][4] = {};
#pragma unroll 1
  for (int ch = 0; ch < ENC_ / 64; ch++) {
    int k0 = ch * 64;
    __syncthreads();
#pragma unroll
    for (int q = 0; q < 4; q++) {
      int idx = tid + q * 256;
      int row = idx >> 4, slot = idx & 15;
      *(float4*)&As[swz(row, slot)] =
          *(const float4*)(Ag + (size_t)(m0 + row) * ENC_ + k0 + slot * 4);
      *(float4*)&Ws[swz(row, slot)] =
          *(const float4*)(Wg + (size_t)(k0 + row) * A_ + n0 + slot * 4);
    }
    __syncthreads();
#pragma unroll
    for (int kk = 0; kk < 16; kk++) {
      float4 av[4], wv[4];
#pragma unroll
      for (int i = 0; i < 4; i++) av[i] = *(float4*)&As[swz(4 * tm + i, kk)];
#pragma unroll
      for (int u = 0; u < 4; u++) wv[u] = *(float4*)&Ws[swz(4 * kk + u, tn)];
      const float* wq = (const float*)wv;
#pragma unroll
      for (int i = 0; i < 4; i++) {
        const float* aq = (const float*)&av[i];
#pragma unroll
        for (int j = 0; j < 4; j++) {
          float s = acc[i][j];
#pragma unroll
          for (int u = 0; u < 4; u++) s = fmaf(aq[u], wq[u * 4 + j], s);
          acc[i][j] = s;
        }
      }
    }
  }
#pragma unroll
  for (int i = 0; i < 4; i++) {
    int m = m0 + 4 * tm + i, n = n0 + 4 * tn;
    float4 bv = *(const float4*)(bias + n);
    float4 o = {acc[i][0] + bv.x, acc[i][1] + bv.y, acc[i][2] + bv.z, acc[i][3] + bv.w};
    *(float4*)(Cg + (size_t)m * A_ + n) = o;
  }
}

__global__ __launch_bounds__(256) void k_logits(const float* __restrict__ h,
    const float* __restrict__ Wout, const float* __restrict__ bout,
    float* __restrict__ out, int t) {
  __shared__ float As[64 * 64], Ws[64 * 64];
  int n0 = blockIdx.x * 64;
  int tid = threadIdx.x, tn = tid & 15, tm = tid >> 4;
  float acc[4][4] = {};
#pragma unroll 1
  for (int ch = 0; ch < D_ / 64; ch++) {
    int k0 = ch * 64;
    __syncthreads();
#pragma unroll
    for (int q = 0; q < 4; q++) {
      int idx = tid + q * 256;
      int row = idx >> 4, slot = idx & 15;
      *(float4*)&As[swz(row, slot)] =
          *(const float4*)(h + (size_t)row * D_ + k0 + slot * 4);
      *(float4*)&Ws[swz(row, slot)] =
          *(const float4*)(Wout + (size_t)(k0 + row) * V_ + n0 + slot * 4);
    }
    __syncthreads();
#pragma unroll
    for (int kk = 0; kk < 16; kk++) {
      float4 av[4], wv[4];
#pragma unroll
      for (int i = 0; i < 4; i++) av[i] = *(float4*)&As[swz(4 * tm + i, kk)];
#pragma unroll
      for (int u = 0; u < 4; u++) wv[u] = *(float4*)&Ws[swz(4 * kk + u, tn)];
      const float* wq = (const float*)wv;
#pragma unroll
      for (int i = 0; i < 4; i++) {
        const float* aq = (const float*)&av[i];
#pragma unroll
        for (int j = 0; j < 4; j++) {
          float s = acc[i][j];
#pragma unroll
          for (int u = 0; u < 4; u++) s = fmaf(aq[u], wq[u * 4 + j], s);
          acc[i][j] = s;
        }
      }
    }
  }
#pragma unroll
  for (int i = 0; i < 4; i++) {
    int m = 4 * tm + i, n = n0 + 4 * tn;
    float4 bv = *(const float4*)(bout + n);
    float4 o = {acc[i][0] + bv.x, acc[i][1] + bv.y, acc[i][2] + bv.z, acc[i][3] + bv.w};
    *(float4*)(out + ((size_t)m * T_ + t) * V_ + n) = o;
  }
}

__global__ __launch_bounds__(256) void k_gates(const float* __restrict__ ctx,
    const float* __restrict__ emb, const float* __restrict__ h,
    const float* __restrict__ Wih, const float* __restrict__ Whh,
    float* __restrict__ gp, int t) {
  __shared__ float As[64 * 64], Ws[64 * 64];
  int n0 = blockIdx.x * 64;
  int sp = blockIdx.y;
  int tid = threadIdx.x, tn = tid & 15, tm = tid >> 4;
  float acc[4][4] = {};
  constexpr int GCH_ = (KX_ / 64) / KSPL;
#pragma unroll 1
  for (int ch = 0; ch < GCH_; ch++) {
    int k0 = sp * (GCH_ * 64) + ch * 64;
    __syncthreads();
#pragma unroll
    for (int q = 0; q < 4; q++) {
      int idx = tid + q * 256;
      int row = idx >> 4, slot = idx & 15;
      int k = k0 + slot * 4;
      float4 xv;
      if (k < ENC_)            xv = *(const float4*)(ctx + (size_t)row * ENC_ + k);
      else if (k < ENC_ + E_)  xv = *(const float4*)(emb + ((size_t)row * NT_ + t) * E_ + (k - ENC_));
      else                     xv = *(const float4*)(h + (size_t)row * D_ + (k - ENC_ - E_));
      *(float4*)&As[swz(row, slot)] = xv;
      int j = n0 + row;
      float4 wv2;
      if (k < ENC_ + E_) wv2 = *(const float4*)(Wih + (size_t)j * (ENC_ + E_) + k);
      else               wv2 = *(const float4*)(Whh + (size_t)j * D_ + (k - ENC_ - E_));
      *(float4*)&Ws[swz(row, slot)] = wv2;
    }
    __syncthreads();
#pragma unroll
    for (int kk = 0; kk < 16; kk++) {
      float4 av[4], wv[4];
#pragma unroll
      for (int i = 0; i < 4; i++) av[i] = *(float4*)&As[swz(4 * tm + i, kk)];
#pragma unroll
      for (int j = 0; j < 4; j++) wv[j] = *(float4*)&Ws[swz(4 * tn + j, kk)];
#pragma unroll
      for (int i = 0; i < 4; i++) {
        const float* aq = (const float*)&av[i];
#pragma unroll
        for (int j = 0; j < 4; j++) {
          const float* wqj = (const float*)&wv[j];
          float s = acc[i][j];
#pragma unroll
          for (int u = 0; u < 4; u++) s = fmaf(aq[u], wqj[u], s);
          acc[i][j] = s;
        }
      }
    }
  }
#pragma unroll
  for (int i = 0; i < 4; i++) {
    int b = 4 * tm + i, j = n0 + 4 * tn;
    float4 o = {acc[i][0], acc[i][1], acc[i][2], acc[i][3]};
    *(float4*)(gp + ((size_t)(sp * B_ + b)) * (4 * D_) + j) = o;
  }
}

__global__ __launch_bounds__(512) void k_att(const float* __restrict__ feat,
    const float* __restrict__ encs, const float* __restrict__ Wdec,
    const float* __restrict__ bdec, const float* __restrict__ wA,
    const float* __restrict__ bA, const float* __restrict__ gp,
    const float* __restrict__ bih, const float* __restrict__ bhh,
    float* __restrict__ h, float* __restrict__ c, float* __restrict__ ctx,
    int do_reduce, int do_att) {
  __shared__ float hs[D_];
  __shared__ float ds[A_];
  __shared__ float sc[P_];
  __shared__ float inv_s;
  int b = blockIdx.x, tid = threadIdx.x;

  if (do_reduce) {
    int d = tid;
    float g0 = 0, g1 = 0, g2 = 0, g3 = 0;
#pragma unroll
    for (int s = 0; s < KSPL; s++) {
      const float* g = gp + (size_t)(s * B_ + b) * (4 * D_);
      g0 += g[d]; g1 += g[D_ + d]; g2 += g[2 * D_ + d]; g3 += g[3 * D_ + d];
    }
    g0 += bih[d] + bhh[d];
    g1 += bih[D_ + d] + bhh[D_ + d];
    g2 += bih[2 * D_ + d] + bhh[2 * D_ + d];
    g3 += bih[3 * D_ + d] + bhh[3 * D_ + d];
    float iv = sigm(g0), fv = sigm(g1), gv = tanhx(g2), ov = sigm(g3);
    float cv = fmaf(fv, c[b * D_ + d], iv * gv);
    float hv = ov * tanhx(cv);
    c[b * D_ + d] = cv;
    h[b * D_ + d] = hv;
    hs[d] = hv;
  } else {
    hs[tid] = h[b * D_ + tid];
  }
  __syncthreads();
  if (!do_att) return;

  {
    int a = tid;
    float s = bdec[a];
#pragma unroll 8
    for (int d = 0; d < D_; d++) s = fmaf(hs[d], Wdec[(size_t)d * A_ + a], s);
    ds[a] = s;
  }
  __syncthreads();

  int wv_ = tid >> 6, ln = tid & 63;
  float bA0 = bA[0];
  for (int p = wv_; p < P_; p += 8) {
    const float* ep = encs + (size_t)(b * P_ + p) * A_;
    float s = 0.f;
#pragma unroll
    for (int a = ln; a < A_; a += 64) s += tanhx(ep[a] + ds[a]) * wA[a];
#pragma unroll
    for (int off = 32; off; off >>= 1) s += __shfl_down(s, off);
    if (ln == 0) sc[p] = s + bA0;
  }
  __syncthreads();

  if (tid == 0) {
    float mx = -1e30f;
    for (int p = 0; p < P_; p++) mx = fmaxf(mx, sc[p]);
    float sum = 0.f;
    for (int p = 0; p < P_; p++) { float ex = __expf(sc[p] - mx); sc[p] = ex; sum += ex; }
    inv_s = 1.0f / sum;
  }
  __syncthreads();

  float inv = inv_s;
  for (int e = tid; e < ENC_; e += 512) {
    const float* fp = feat + (size_t)b * P_ * ENC_ + e;
    float s = 0.f;
#pragma unroll
    for (int p = 0; p < P_; p++) s = fmaf(fp[(size_t)p * ENC_], sc[p], s);
    ctx[b * ENC_ + e] = s * inv;
  }
}

// ================= host =================

extern "C" void kernel_launch(void* const* d_in, const int* in_sizes, int n_in,
                              void* d_out, int out_size, void* d_ws, size_t ws_size,
                              hipStream_t stream) {
  const float* features = (const float*)d_in[0];
  const int*   captions = (const int*)d_in[1];
  const float* table    = (const float*)d_in[2];
  const float* Wih  = (const float*)d_in[3];
  const float* bih  = (const float*)d_in[4];
  const float* Whh  = (const float*)d_in[5];
  const float* bhh  = (const float*)d_in[6];
  const float* Winh = (const float*)d_in[7];
  const float* binh = (const float*)d_in[8];
  const float* Winc = (const float*)d_in[9];
  const float* binc = (const float*)d_in[10];
  const float* Wenc = (const float*)d_in[11];
  const float* benc = (const float*)d_in[12];
  const float* Wdec = (const float*)d_in[13];
  const float* bdec = (const float*)d_in[14];
  const float* wA   = (const float*)d_in[15];
  const float* bA   = (const float*)d_in[16];
  const float* Wout = (const float*)d_in[17];
  const float* bout = (const float*)d_in[18];
  float* out = (float*)d_out;

  constexpr size_t F_ENC = (size_t)B_ * P_ * A_;
  constexpr size_t F_C   = (size_t)B_ * D_;
  constexpr size_t F_GP  = (size_t)KSPL * B_ * 4 * D_;   // = WiT size
  constexpr size_t U_WOT = (size_t)V_ * D_;
  constexpr size_t U_WG  = (size_t)(4 * D_) * KX_;
  constexpr size_t U_EMBT = (size_t)B_ * E_;
  constexpr size_t U_CTX = (size_t)B_ * ENC_;
  constexpr size_t U_FEAT = (size_t)B_ * P_ * ENC_;
  constexpr size_t U_WET = (size_t)A_ * ENC_;
  constexpr size_t U_WDT = (size_t)A_ * D_;
  constexpr size_t U_HALL = (size_t)NT_ * B_ * D_;
  constexpr size_t NEED_BYTES =
      (F_ENC + 2 * F_C + F_GP) * 4 +
      (U_WOT + U_WG + U_EMBT + U_CTX + U_FEAT + U_WET + U_HALL) * 2;
  constexpr size_t NEED2 = NEED_BYTES + U_WDT * 2;   // 73,269,248 = R1-proven ws

  if (ws_size >= NEED2) {
    float* ws = (float*)d_ws;
    float* enc_states = ws;
    float* cbuf0  = enc_states + F_ENC;
    float* cbuf1  = cbuf0 + F_C;
    float* gparts = cbuf1 + F_C;                    // WiT (prologue) / gp (loop)
    u16* WoT   = (u16*)(gparts + F_GP);
    u16* Wg    = WoT + U_WOT;
    u16* embt  = Wg + U_WG;
    u16* ctxb  = embt + U_EMBT;
    u16* featb = ctxb + U_CTX;
    u16* WeT   = featb + U_FEAT;
    u16* hall  = WeT + U_WET;
    u16* WdT   = hall + U_HALL;                     // in NEED2 headroom
    u16* WiT   = (u16*)gparts;                      // prologue-only overlay
    u16* mfb   = ctxb;                              // prologue-only overlay
    float* cb[2] = {cbuf0, cbuf1};

    // ---- prologue: 3 launches ----
    k_pro1s<<<PRO1_BLOCKS, 256, 0, stream>>>(features, Winh, Winc, Wenc, Wdec,
                                             Wih, Whh, mfb, featb, WiT, WeT,
                                             WdT, Wg);
    k_trW<<<dim3(V_ / 128, D_ / 256), 256, 0, stream>>>(Wout, WoT);
    k_pro2<<<408, 256, 0, stream>>>(mfb, WiT, binh, binc, hall /*h0*/, cbuf0,
                                    featb, WeT, benc, enc_states);

    // ---- 2-launch step loop (R6 config; h lives in hall) ----
    for (int t = 0; t < NT_; t++) {
      u16* hcur = hall + (size_t)(t > 0 ? t - 1 : 0) * B_ * D_;
      const float* cin = cb[(t > 0 ? (t - 1) : 0) & 1];
      float* cout = cb[t & 1];
      k_att3<<<dim3(64, 2), 512, 0, stream>>>(featb, enc_states, WdT, bdec, wA,
                                              bA, gparts, bih, bhh, cin, cout,
                                              hcur, ctxb, captions, table,
                                              embt, t, t > 0 ? 1 : 0, 1);
      k_gates_bf<<<dim3(32, KSPL), 256, 0, stream>>>(ctxb, embt, hcur, Wg,
                                                     gparts);
    }
    // final reduce -> hall[18]
    k_att3<<<dim3(64, 1), 512, 0, stream>>>(featb, enc_states, WdT, bdec, wA,
                                            bA, gparts, bih, bhh,
                                            cb[(NT_ - 1) & 1], cb[NT_ & 1],
                                            hall + (size_t)(NT_ - 1) * B_ * D_,
                                            ctxb, captions, table, embt, 0,
                                            1, 0);
    // ---- batched logits, s-clustered write order ----
    k_logits6<<<dim3(128, T_), 256, 0, stream>>>(hall, WoT, bout, out);
  } else {
    // fp32 fallback (R0 path)
    float* ws = (float*)d_ws;
    float* enc_states = ws;
    float* mean_f = enc_states + (size_t)B_ * P_ * A_;
    float* emb    = mean_f + (size_t)B_ * ENC_;
    float* h      = emb + (size_t)B_ * NT_ * E_;
    float* c      = h + (size_t)B_ * D_;
    float* ctx    = c + (size_t)B_ * D_;
    float* gparts = ctx + (size_t)B_ * ENC_;

    k_mean<<<512, 256, 0, stream>>>(features, mean_f);
    k_emb<<<2432, 256, 0, stream>>>(captions, table, emb);
    k_init<<<dim3(2, 64, 2), 256, 0, stream>>>(mean_f, Winh, binh, Winc, binc, h, c);
    k_enc<<<dim3(49, 8), 256, 0, stream>>>(features, Wenc, benc, enc_states);
    k_zero_last<<<2000, 256, 0, stream>>>(out);

    for (int t = 0; t < NT_; t++) {
      k_att<<<64, 512, 0, stream>>>(features, enc_states, Wdec, bdec, wA, bA,
                                    gparts, bih, bhh, h, c, ctx, t > 0 ? 1 : 0, 1);
      if (t > 0)
        k_logits<<<500, 256, 0, stream>>>(h, Wout, bout, out, t - 1);
      k_gates<<<dim3(32, KSPL), 256, 0, stream>>>(ctx, emb, h, Wih, Whh, gparts, t);
    }
    k_att<<<64, 512, 0, stream>>>(features, enc_states, Wdec, bdec, wA, bA,
                                  gparts, bih, bhh, h, c, ctx, 1, 0);
    k_logits<<<500, 256, 0, stream>>>(h, Wout, bout, out, NT_ - 1);
  }
}

// Round 18
// 1089.780 us; speedup vs baseline: 1.0488x; 1.0488x over previous
//
#include <hip/hip_runtime.h>

constexpr int B_   = 64;
constexpr int P_   = 49;
constexpr int T_   = 20;
constexpr int V_   = 32000;
constexpr int E_   = 512;
constexpr int D_   = 512;
constexpr int A_   = 512;
constexpr int ENC_ = 2048;
constexpr int NT_  = T_ - 1;
constexpr int KX_  = ENC_ + E_ + D_;   // 3072
constexpr int KSPL = 8;                // gates split-K (R6-proven)

#define DI __device__ __forceinline__

using u16 = unsigned short;
typedef short   bf16x8 __attribute__((ext_vector_type(8)));
typedef float   f32x4  __attribute__((ext_vector_type(4)));
typedef u16     u16x4  __attribute__((ext_vector_type(4)));
typedef u16     u16x2  __attribute__((ext_vector_type(2)));

DI float sigm(float x) { return 1.0f / (1.0f + __expf(-x)); }
DI float tanhx(float x) {
  x = fminf(15.0f, fmaxf(-15.0f, x));
  float e = __expf(2.0f * x);
  return (e - 1.0f) / (e + 1.0f);
}
DI u16 f2bf(float x) {
  union { float f; unsigned u; } v{x};
  unsigned r = v.u + 0x7FFF + ((v.u >> 16) & 1);   // RNE
  return (u16)(r >> 16);
}
DI float bf2f(u16 x) {
  union { unsigned u; float f; } v;
  v.u = ((unsigned)x) << 16;
  return v.f;
}
DI f32x4 mfma16(bf16x8 a, bf16x8 b, f32x4 c) {
  return __builtin_amdgcn_mfma_f32_16x16x32_bf16(a, b, c, 0, 0, 0);
}

// ========== P1-small: fused light converters (uniform 4.2KB smem) ==========
constexpr int PRO1_BLOCKS = 16256;

DI void dev_tr_cvt(const float* in, u16* outp, int R, int C, int bx, int by,
                   float (*tbuf)[33]) {
  int tx = threadIdx.x & 31, ty = threadIdx.x >> 5;
  int c0 = bx * 32, r0 = by * 32;
#pragma unroll
  for (int i = 0; i < 4; i++)
    tbuf[ty + 8 * i][tx] = in[(size_t)(r0 + ty + 8 * i) * C + c0 + tx];
  __syncthreads();
#pragma unroll
  for (int i = 0; i < 4; i++)
    outp[(size_t)(c0 + ty + 8 * i) * R + r0 + tx] = f2bf(tbuf[tx][ty + 8 * i]);
}

__global__ __launch_bounds__(256) void k_pro1s(
    const float* __restrict__ feat, const float* __restrict__ Winh,
    const float* __restrict__ Winc, const float* __restrict__ Wenc,
    const float* __restrict__ Wdec, const float* __restrict__ Wih,
    const float* __restrict__ Whh, u16* __restrict__ mfb,
    u16* __restrict__ featb, u16* __restrict__ WiT, u16* __restrict__ WeT,
    u16* __restrict__ WdT, u16* __restrict__ Wg) {
  __shared__ float tbuf[32][33];
  int bid = blockIdx.x;
  if (bid < 6272) {                       // cvt4 feat
    int i = bid * 256 + threadIdx.x;
    float4 v = ((const float4*)feat)[i];
    u16x4 r = {f2bf(v.x), f2bf(v.y), f2bf(v.z), f2bf(v.w)};
    ((u16x4*)featb)[i] = r;
  } else if (bid < 6784) {                // mean
    int idx = (bid - 6272) * 256 + threadIdx.x;
    int b = idx >> 11, e = idx & (ENC_ - 1);
    const float* f = feat + (size_t)b * P_ * ENC_ + e;
    float s = 0.f;
#pragma unroll
    for (int p = 0; p < P_; p++) s += f[(size_t)p * ENC_];
    mfb[idx] = f2bf(s * (1.0f / P_));
  } else if (bid < 7808) {                // tr Winh
    int l = bid - 6784;
    dev_tr_cvt(Winh, WiT, ENC_, D_, l & 15, l >> 4, tbuf);
  } else if (bid < 8832) {                // tr Winc
    int l = bid - 7808;
    dev_tr_cvt(Winc, WiT + (size_t)D_ * ENC_, ENC_, D_, l & 15, l >> 4, tbuf);
  } else if (bid < 9856) {                // tr Wenc
    int l = bid - 8832;
    dev_tr_cvt(Wenc, WeT, ENC_, A_, l & 15, l >> 4, tbuf);
  } else if (bid < 10112) {               // tr Wdec
    int l = bid - 9856;
    dev_tr_cvt(Wdec, WdT, D_, A_, l & 15, l >> 4, tbuf);
  } else {                                // wg4
    int i = (bid - 10112) * 256 + threadIdx.x;
    int j = i / 768, rem = i - j * 768;
    int k = rem * 4;
    const float* src = (k < ENC_ + E_) ? (Wih + (size_t)j * (ENC_ + E_) + k)
                                       : (Whh + (size_t)j * D_ + (k - ENC_ - E_));
    float4 v = *(const float4*)src;
    u16x4 r = {f2bf(v.x), f2bf(v.y), f2bf(v.z), f2bf(v.w)};
    ((u16x4*)Wg)[i] = r;
  }
}

// Wout transpose: f32 [512][32000] -> bf16 [32000][512]; 512B-contiguous
__global__ __launch_bounds__(256) void k_trW(const float* __restrict__ in,
                                             u16* __restrict__ outp) {
  __shared__ u16 ld[128][264];
  int v0 = blockIdx.x * 128, k0 = blockIdx.y * 256;
  int vf = (threadIdx.x & 31) * 4, kk = threadIdx.x >> 5;
#pragma unroll 4
  for (int p = 0; p < 32; p++) {
    int k = kk + p * 8;
    float4 v = *(const float4*)(in + (size_t)(k0 + k) * V_ + v0 + vf);
    ld[vf + 0][k] = f2bf(v.x);
    ld[vf + 1][k] = f2bf(v.y);
    ld[vf + 2][k] = f2bf(v.z);
    ld[vf + 3][k] = f2bf(v.w);
  }
  __syncthreads();
  int v = threadIdx.x >> 1, h = threadIdx.x & 1;
  u16* op = outp + (size_t)(v0 + v) * D_ + k0 + h * 128;
#pragma unroll
  for (int i = 0; i < 16; i++)
    *(bf16x8*)(op + i * 8) = *(const bf16x8*)(&ld[v][h * 128 + i * 8]);
}

// ========== P2: init_bf (16 blocks; h0 -> hall[0]) + enc_bf (392) =========

__global__ __launch_bounds__(256) void k_pro2(const u16* __restrict__ mfb,
    const u16* __restrict__ WiT, const float* __restrict__ binh,
    const float* __restrict__ binc, u16* __restrict__ hall0,
    float* __restrict__ c, const u16* __restrict__ featb,
    const u16* __restrict__ WeT, const float* __restrict__ benc,
    float* __restrict__ encs) {
  int wid = threadIdx.x >> 6, lane = threadIdx.x & 63;
  int l16 = lane & 15, lk = lane >> 4;
  if (blockIdx.x < 16) {   // init: h0|c0 = mfb @ WiT
    int n0 = blockIdx.x * 64 + wid * 16;
    const u16* bp = WiT + (size_t)(n0 + l16) * ENC_ + 8 * lk;
    const u16* ap = mfb + (size_t)l16 * ENC_ + 8 * lk;
    f32x4 acc[4] = {};
#pragma unroll 4
    for (int kc = 0; kc < ENC_; kc += 32) {
      bf16x8 b = *(const bf16x8*)(bp + kc);
#pragma unroll
      for (int mf = 0; mf < 4; mf++) {
        bf16x8 a = *(const bf16x8*)(ap + (size_t)mf * 16 * ENC_ + kc);
        acc[mf] = mfma16(a, b, acc[mf]);
      }
    }
    int n = n0 + l16;
#pragma unroll
    for (int mf = 0; mf < 4; mf++) {
      int m = mf * 16 + 4 * lk;
#pragma unroll
      for (int r = 0; r < 4; r++) {
        float v = acc[mf][r];
        if (n < D_) hall0[(size_t)(m + r) * D_ + n] = f2bf(v + binh[n]);
        else        c[(size_t)(m + r) * D_ + (n - D_)] = v + binc[n - D_];
      }
    }
  } else {                 // enc_states GEMM
    int l = blockIdx.x - 16;
    int m0 = (l % 49) * 64, n0 = (l / 49) * 64 + wid * 16;
    const u16* ap = featb + (size_t)(m0 + l16) * ENC_ + 8 * lk;
    const u16* bp = WeT + (size_t)(n0 + l16) * ENC_ + 8 * lk;
    f32x4 acc[4] = {};
#pragma unroll 8
    for (int i = 0; i < ENC_ / 32; i++) {
      int kc = i * 32;
      bf16x8 b = *(const bf16x8*)(bp + kc);
#pragma unroll
      for (int mf = 0; mf < 4; mf++) {
        bf16x8 a = *(const bf16x8*)(ap + (size_t)mf * 16 * ENC_ + kc);
        acc[mf] = mfma16(a, b, acc[mf]);
      }
    }
    float bv = benc[n0 + l16];
#pragma unroll
    for (int mf = 0; mf < 4; mf++) {
      int m = m0 + mf * 16 + 4 * lk;
#pragma unroll
      for (int r = 0; r < 4; r++)
        encs[(size_t)(m + r) * A_ + n0 + l16] = acc[mf][r] + bv;
    }
  }
}

// ====== loop: k_att3 (R6-proven grid (64,2)) + k_gates_bf (32,8) ==========

__global__ __launch_bounds__(512) void k_att3(const u16* __restrict__ featb,
    const float* __restrict__ encs, const u16* __restrict__ WdT,
    const float* __restrict__ bdec, const float* __restrict__ wA,
    const float* __restrict__ bA, const float* __restrict__ gp,
    const float* __restrict__ bih, const float* __restrict__ bhh,
    const float* __restrict__ c_in, float* __restrict__ c_out,
    u16* __restrict__ hcur, u16* __restrict__ ctxb,
    const int* __restrict__ cap, const float* __restrict__ tab,
    u16* __restrict__ embt, int t, int do_reduce, int do_att) {
  __shared__ u16 hsb[D_];
  __shared__ float ds[A_];
  __shared__ float sc[P_];
  __shared__ float inv_s;
  int b = blockIdx.x, y = blockIdx.y, tid = threadIdx.x;

  if (do_att && y == 0) {   // emb gather for THIS step
    int tok = cap[b * T_ + t];
    embt[(size_t)b * E_ + tid] = f2bf(tab[(size_t)tok * E_ + tid]);
  }

  if (do_reduce) {
    int d = tid;
    float g0 = 0, g1 = 0, g2 = 0, g3 = 0;
#pragma unroll
    for (int s = 0; s < KSPL; s++) {
      const float* g = gp + (size_t)(s * B_ + b) * (4 * D_);
      g0 += g[d]; g1 += g[D_ + d]; g2 += g[2 * D_ + d]; g3 += g[3 * D_ + d];
    }
    g0 += bih[d] + bhh[d];
    g1 += bih[D_ + d] + bhh[D_ + d];
    g2 += bih[2 * D_ + d] + bhh[2 * D_ + d];
    g3 += bih[3 * D_ + d] + bhh[3 * D_ + d];
    float iv = sigm(g0), fv = sigm(g1), gv = tanhx(g2), ov = sigm(g3);
    float cv = fmaf(fv, c_in[b * D_ + d], iv * gv);
    float hv = ov * tanhx(cv);
    u16 hb = f2bf(hv);
    hsb[d] = hb;
    if (y == 0) {
      c_out[b * D_ + d] = cv;
      hcur[b * D_ + d] = hb;
    }
  } else {
    hsb[tid] = hcur[b * D_ + tid];
  }
  __syncthreads();
  if (!do_att) return;

  // dec = h @ Wdec + bdec (broadcast-row MFMA)
  {
    int w = tid >> 6, lane = tid & 63, l16 = lane & 15, lk = lane >> 4;
#pragma unroll
    for (int f = 0; f < 4; f++) {
      int n = w * 64 + f * 16 + l16;
      const u16* bp = WdT + (size_t)n * D_ + 8 * lk;
      f32x4 acc = {};
#pragma unroll
      for (int kc = 0; kc < D_; kc += 32) {
        bf16x8 av = *(const bf16x8*)(hsb + kc + 8 * lk);
        bf16x8 bv = *(const bf16x8*)(bp + kc);
        acc = mfma16(av, bv, acc);
      }
      if (lk == 0) ds[n] = acc[0] + bdec[n];
    }
  }
  __syncthreads();

  // scores
  {
    int wv_ = tid >> 6, ln = tid & 63;
    float bA0 = bA[0];
    for (int p = wv_; p < P_; p += 8) {
      const float* ep = encs + (size_t)(b * P_ + p) * A_;
      float s = 0.f;
#pragma unroll
      for (int a = ln; a < A_; a += 64) s += tanhx(ep[a] + ds[a]) * wA[a];
#pragma unroll
      for (int off = 32; off; off >>= 1) s += __shfl_down(s, off);
      if (ln == 0) sc[p] = s + bA0;
    }
  }
  __syncthreads();
  if (tid == 0) {
    float mx = -1e30f;
    for (int p = 0; p < P_; p++) mx = fmaxf(mx, sc[p]);
    float sum = 0.f;
    for (int p = 0; p < P_; p++) { float ex = __expf(sc[p] - mx); sc[p] = ex; sum += ex; }
    inv_s = 1.0f / sum;
  }
  __syncthreads();

  // ctx: u16x2 per thread, y-half of ENC (R6-proven)
  {
    float inv = inv_s;
    int e = y * 1024 + tid * 2;
    const u16* fp = featb + (size_t)b * P_ * ENC_ + e;
    float s0 = 0.f, s1 = 0.f;
#pragma unroll
    for (int p = 0; p < P_; p++) {
      u16x2 w = *(const u16x2*)(fp + (size_t)p * ENC_);
      s0 = fmaf(bf2f(w.x), sc[p], s0);
      s1 = fmaf(bf2f(w.y), sc[p], s1);
    }
    u16x2 o = {f2bf(s0 * inv), f2bf(s1 * inv)};
    *(u16x2*)(ctxb + b * ENC_ + e) = o;
  }
}

__global__ __launch_bounds__(256) void k_gates_bf(const u16* __restrict__ ctxb,
    const u16* __restrict__ embt, const u16* __restrict__ hcur,
    const u16* __restrict__ Wg, float* __restrict__ gp) {
  int wid = threadIdx.x >> 6, lane = threadIdx.x & 63;
  int j0 = blockIdx.x * 64 + wid * 16;
  int sp = blockIdx.y;
  int l16 = lane & 15, lk = lane >> 4;
  const u16* bp = Wg + (size_t)(j0 + l16) * KX_ + 8 * lk;
  f32x4 acc[4] = {};
#pragma unroll
  for (int i = 0; i < KX_ / KSPL / 32; i++) {   // 12 chunks
    int kc = sp * (KX_ / KSPL) + i * 32;
    int k = kc + 8 * lk;
    bf16x8 b = *(const bf16x8*)(bp + kc);
#pragma unroll
    for (int mf = 0; mf < 4; mf++) {
      int row = mf * 16 + l16;
      const u16* src;
      if (k < ENC_)            src = ctxb + (size_t)row * ENC_ + k;
      else if (k < ENC_ + E_)  src = embt + (size_t)row * E_ + (k - ENC_);
      else                     src = hcur + (size_t)row * D_ + (k - ENC_ - E_);
      bf16x8 a = *(const bf16x8*)src;
      acc[mf] = mfma16(a, b, acc[mf]);
    }
  }
#pragma unroll
  for (int mf = 0; mf < 4; mf++) {
    int m = mf * 16 + 4 * lk;
#pragma unroll
    for (int r = 0; r < 4; r++)
      gp[((size_t)sp * B_ + m + r) * (4 * D_) + j0 + l16] = acc[mf][r];
  }
}

// ====== batched logits v7: windowed hybrid decode ======
// 8 windows x 320 blocks = {32 nt x 10 s}. Per window: each XCD holds only
// 4 WoT slices (1MB << L2, vs R17's 4MB thrash), reused 10x; concurrent
// writes cover 32KB contiguous per output row (vs R16's 1KB scatter).
// s==19 slot of sg=1 windows carries the zero-fill plane.

__global__ __launch_bounds__(256) void k_logits7(const u16* __restrict__ hall,
    const u16* __restrict__ WoT, const float* __restrict__ bout,
    float* __restrict__ out) {
  __shared__ float tile[64 * 264];
  int L = blockIdx.x;            // 0..2559
  int win = L / 320, ww = L % 320;
  int ntg = win >> 1, sg = win & 1;
  int nt = ntg * 32 + (ww & 31); // XCD = nt%8 = (ww&31)%8, 4 slices/XCD/window
  int s  = sg * 10 + (ww >> 5);  // 0..9 | 10..19
  if (nt >= 125) return;
  if (s == NT_) {   // t = T-1 zero-fill plane
    int tr = threadIdx.x >> 2, tc = threadIdx.x & 3;
    f32x4 z = {0.f, 0.f, 0.f, 0.f};
    float* op = out + ((size_t)tr * T_ + NT_) * V_ + nt * 256;
#pragma unroll
    for (int j = 0; j < 16; j++)
      __builtin_nontemporal_store(z, (f32x4*)(op + (tc + j * 4) * 4));
    return;
  }
  int w = threadIdx.x >> 6, lane = threadIdx.x & 63;
  int l16 = lane & 15, lk = lane >> 4;
  const u16* ap0 = hall + (size_t)s * B_ * D_ + (size_t)l16 * D_ + 8 * lk;
  int ncol0 = nt * 256 + w * 64;
#pragma unroll 1
  for (int ch = 0; ch < 4; ch++) {
    int col = ncol0 + ch * 16 + l16;
    const u16* bp = WoT + (size_t)col * D_ + 8 * lk;
    f32x4 acc[4] = {};
#pragma unroll
    for (int kc = 0; kc < 16; kc++) {
      bf16x8 b = *(const bf16x8*)(bp + kc * 32);
#pragma unroll
      for (int mf = 0; mf < 4; mf++) {
        bf16x8 a = *(const bf16x8*)(ap0 + (size_t)mf * 16 * D_ + kc * 32);
        acc[mf] = mfma16(a, b, acc[mf]);
      }
    }
    float bv = bout[col];
#pragma unroll
    for (int mf = 0; mf < 4; mf++)
#pragma unroll
      for (int rr = 0; rr < 4; rr++)
        tile[(mf * 16 + 4 * lk + rr) * 264 + w * 64 + ch * 16 + l16] =
            acc[mf][rr] + bv;
  }
  __syncthreads();
  int tr = threadIdx.x >> 2, tc = threadIdx.x & 3;
  float* op = out + ((size_t)tr * T_ + s) * V_ + nt * 256;
  const float* lp = &tile[tr * 264];
#pragma unroll
  for (int j = 0; j < 16; j++) {
    int cc = (tc + j * 4) * 4;
    __builtin_nontemporal_store(*(const f32x4*)(lp + cc), (f32x4*)(op + cc));
  }
}

// ================= fp32 fallback path (R0 kernels) =================

DI int swz(int row, int slot) { return row * 64 + ((slot ^ (row >> 2)) << 2); }

__global__ __launch_bounds__(256) void k_mean(const float* __restrict__ feat,
                                              float* __restrict__ mf) {
  int idx = blockIdx.x * 256 + threadIdx.x;
  int b = idx >> 11, e = idx & (ENC_ - 1);
  const float* f = feat + (size_t)b * P_ * ENC_ + e;
  float s = 0.f;
#pragma unroll
  for (int p = 0; p < P_; p++) s += f[(size_t)p * ENC_];
  mf[idx] = s * (1.0f / P_);
}

__global__ __launch_bounds__(256) void k_emb(const int* __restrict__ cap,
                                             const float* __restrict__ tab,
                                             float* __restrict__ emb) {
  int idx = blockIdx.x * 256 + threadIdx.x;
  int e  = idx & (E_ - 1);
  int bt = idx >> 9;
  int b = bt / NT_, t = bt - b * NT_;
  int tok = cap[b * T_ + t];
  emb[idx] = tab[(size_t)tok * E_ + e];
}

__global__ __launch_bounds__(256) void k_init(const float* __restrict__ mf,
    const float* __restrict__ Wh, const float* __restrict__ bh,
    const float* __restrict__ Wc, const float* __restrict__ bc,
    float* __restrict__ h, float* __restrict__ c) {
  __shared__ float ms[ENC_];
  int b = blockIdx.y;
  for (int i = threadIdx.x; i < ENC_; i += 256) ms[i] = mf[b * ENC_ + i];
  __syncthreads();
  int d = blockIdx.x * 256 + threadIdx.x;
  const float* W = blockIdx.z ? Wc : Wh;
  float s = (blockIdx.z ? bc : bh)[d];
#pragma unroll 8
  for (int e = 0; e < ENC_; e++) s = fmaf(ms[e], W[(size_t)e * D_ + d], s);
  (blockIdx.z ? c : h)[b * D_ + d] = s;
}

__global__ __launch_bounds__(256) void k_zero_last(float* __restrict__ out) {
  int i = blockIdx.x * 256 + threadIdx.x;
  int b = i / 8000, v4 = i - b * 8000;
  float4 z = {0.f, 0.f, 0.f, 0.f};
  *(float4*)(out + ((size_t)b * T_ + (T_ - 1)) * V_ + (size_t)v4 * 4) = z;
}

__global__ __launch_bounds__(256) void k_enc(const float* __restrict__ Ag,
    const float* __restrict__ Wg, const float* __restrict__ bias,
    float* __restrict__ Cg) {
  __shared__ float As[64 * 64], Ws[64 * 64];
  int m0 = blockIdx.x * 64, n0 = blockIdx.y * 64;
  int tid = threadIdx.x, tn = tid & 15, tm = tid >> 4;
  float acc[4][4] = {};
#pragma unroll 1
  for (int ch = 0; ch < ENC_ / 64; ch++) {
    int k0 = ch * 64;
    __syncthreads();
#pragma unroll
    for (int q = 0; q < 4; q++) {
      int idx = tid + q * 256;
      int row = idx >> 4, slot = idx & 15;
      *(float4*)&As[swz(row, slot)] =
          *(const float4*)(Ag + (size_t)(m0 + row) * ENC_ + k0 + slot * 4);
      *(float4*)&Ws[swz(row, slot)] =
          *(const float4*)(Wg + (size_t)(k0 + row) * A_ + n0 + slot * 4);
    }
    __syncthreads();
#pragma unroll
    for (int kk = 0; kk < 16; kk++) {
      float4 av[4], wv[4];
#pragma unroll
      for (int i = 0; i < 4; i++) av[i] = *(float4*)&As[swz(4 * tm + i, kk)];
#pragma unroll
      for (int u = 0; u < 4; u++) wv[u] = *(float4*)&Ws[swz(4 * kk + u, tn)];
      const float* wq = (const float*)wv;
#pragma unroll
      for (int i = 0; i < 4; i++) {
        const float* aq = (const float*)&av[i];
#pragma unroll
        for (int j = 0; j < 4; j++) {
          float s = acc[i][j];
#pragma unroll
          for (int u = 0; u < 4; u++) s = fmaf(aq[u], wq[u * 4 + j], s);
          acc[i][j] = s;
        }
      }
    }
  }
#pragma unroll
  for (int i = 0; i < 4; i++) {
    int m = m0 + 4 * tm + i, n = n0 + 4 * tn;
    float4 bv = *(const float4*)(bias + n);
    float4 o = {acc[i][0] + bv.x, acc[i][1] + bv.y, acc[i][2] + bv.z, acc[i][3] + bv.w};
    *(float4*)(Cg + (size_t)m * A_ + n) = o;
  }
}

__global__ __launch_bounds__(256) void k_logits(const float* __restrict__ h,
    const float* __restrict__ Wout, const float* __restrict__ bout,
    float* __restrict__ out, int t) {
  __shared__ float As[64 * 64], Ws[64 * 64];
  int n0 = blockIdx.x * 64;
  int tid = threadIdx.x, tn = tid & 15, tm = tid >> 4;
  float acc[4][4] = {};
#pragma unroll 1
  for (int ch = 0; ch < D_ / 64; ch++) {
    int k0 = ch * 64;
    __syncthreads();
#pragma unroll
    for (int q = 0; q < 4; q++) {
      int idx = tid + q * 256;
      int row = idx >> 4, slot = idx & 15;
      *(float4*)&As[swz(row, slot)] =
          *(const float4*)(h + (size_t)row * D_ + k0 + slot * 4);
      *(float4*)&Ws[swz(row, slot)] =
          *(const float4*)(Wout + (size_t)(k0 + row) * V_ + n0 + slot * 4);
    }
    __syncthreads();
#pragma unroll
    for (int kk = 0; kk < 16; kk++) {
      float4 av[4], wv[4];
#pragma unroll
      for (int i = 0; i < 4; i++) av[i] = *(float4*)&As[swz(4 * tm + i, kk)];
#pragma unroll
      for (int u = 0; u < 4; u++) wv[u] = *(float4*)&Ws[swz(4 * kk + u, tn)];
      const float* wq = (const float*)wv;
#pragma unroll
      for (int i = 0; i < 4; i++) {
        const float* aq = (const float*)&av[i];
#pragma unroll
        for (int j = 0; j < 4; j++) {
          float s = acc[i][j];
#pragma unroll
          for (int u = 0; u < 4; u++) s = fmaf(aq[u], wq[u * 4 + j], s);
          acc[i][j] = s;
        }
      }
    }
  }
#pragma unroll
  for (int i = 0; i < 4; i++) {
    int m = 4 * tm + i, n = n0 + 4 * tn;
    float4 bv = *(const float4*)(bout + n);
    float4 o = {acc[i][0] + bv.x, acc[i][1] + bv.y, acc[i][2] + bv.z, acc[i][3] + bv.w};
    *(float4*)(out + ((size_t)m * T_ + t) * V_ + n) = o;
  }
}

__global__ __launch_bounds__(256) void k_gates(const float* __restrict__ ctx,
    const float* __restrict__ emb, const float* __restrict__ h,
    const float* __restrict__ Wih, const float* __restrict__ Whh,
    float* __restrict__ gp, int t) {
  __shared__ float As[64 * 64], Ws[64 * 64];
  int n0 = blockIdx.x * 64;
  int sp = blockIdx.y;
  int tid = threadIdx.x, tn = tid & 15, tm = tid >> 4;
  float acc[4][4] = {};
  constexpr int GCH_ = (KX_ / 64) / KSPL;
#pragma unroll 1
  for (int ch = 0; ch < GCH_; ch++) {
    int k0 = sp * (GCH_ * 64) + ch * 64;
    __syncthreads();
#pragma unroll
    for (int q = 0; q < 4; q++) {
      int idx = tid + q * 256;
      int row = idx >> 4, slot = idx & 15;
      int k = k0 + slot * 4;
      float4 xv;
      if (k < ENC_)            xv = *(const float4*)(ctx + (size_t)row * ENC_ + k);
      else if (k < ENC_ + E_)  xv = *(const float4*)(emb + ((size_t)row * NT_ + t) * E_ + (k - ENC_));
      else                     xv = *(const float4*)(h + (size_t)row * D_ + (k - ENC_ - E_));
      *(float4*)&As[swz(row, slot)] = xv;
      int j = n0 + row;
      float4 wv2;
      if (k < ENC_ + E_) wv2 = *(const float4*)(Wih + (size_t)j * (ENC_ + E_) + k);
      else               wv2 = *(const float4*)(Whh + (size_t)j * D_ + (k - ENC_ - E_));
      *(float4*)&Ws[swz(row, slot)] = wv2;
    }
    __syncthreads();
#pragma unroll
    for (int kk = 0; kk < 16; kk++) {
      float4 av[4], wv[4];
#pragma unroll
      for (int i = 0; i < 4; i++) av[i] = *(float4*)&As[swz(4 * tm + i, kk)];
#pragma unroll
      for (int j = 0; j < 4; j++) wv[j] = *(float4*)&Ws[swz(4 * tn + j, kk)];
#pragma unroll
      for (int i = 0; i < 4; i++) {
        const float* aq = (const float*)&av[i];
#pragma unroll
        for (int j = 0; j < 4; j++) {
          const float* wqj = (const float*)&wv[j];
          float s = acc[i][j];
#pragma unroll
          for (int u = 0; u < 4; u++) s = fmaf(aq[u], wqj[u], s);
          acc[i][j] = s;
        }
      }
    }
  }
#pragma unroll
  for (int i = 0; i < 4; i++) {
    int b = 4 * tm + i, j = n0 + 4 * tn;
    float4 o = {acc[i][0], acc[i][1], acc[i][2], acc[i][3]};
    *(float4*)(gp + ((size_t)(sp * B_ + b)) * (4 * D_) + j) = o;
  }
}

__global__ __launch_bounds__(512) void k_att(const float* __restrict__ feat,
    const float* __restrict__ encs, const float* __restrict__ Wdec,
    const float* __restrict__ bdec, const float* __restrict__ wA,
    const float* __restrict__ bA, const float* __restrict__ gp,
    const float* __restrict__ bih, const float* __restrict__ bhh,
    float* __restrict__ h, float* __restrict__ c, float* __restrict__ ctx,
    int do_reduce, int do_att) {
  __shared__ float hs[D_];
  __shared__ float ds[A_];
  __shared__ float sc[P_];
  __shared__ float inv_s;
  int b = blockIdx.x, tid = threadIdx.x;

  if (do_reduce) {
    int d = tid;
    float g0 = 0, g1 = 0, g2 = 0, g3 = 0;
#pragma unroll
    for (int s = 0; s < KSPL; s++) {
      const float* g = gp + (size_t)(s * B_ + b) * (4 * D_);
      g0 += g[d]; g1 += g[D_ + d]; g2 += g[2 * D_ + d]; g3 += g[3 * D_ + d];
    }
    g0 += bih[d] + bhh[d];
    g1 += bih[D_ + d] + bhh[D_ + d];
    g2 += bih[2 * D_ + d] + bhh[2 * D_ + d];
    g3 += bih[3 * D_ + d] + bhh[3 * D_ + d];
    float iv = sigm(g0), fv = sigm(g1), gv = tanhx(g2), ov = sigm(g3);
    float cv = fmaf(fv, c[b * D_ + d], iv * gv);
    float hv = ov * tanhx(cv);
    c[b * D_ + d] = cv;
    h[b * D_ + d] = hv;
    hs[d] = hv;
  } else {
    hs[tid] = h[b * D_ + tid];
  }
  __syncthreads();
  if (!do_att) return;

  {
    int a = tid;
    float s = bdec[a];
#pragma unroll 8
    for (int d = 0; d < D_; d++) s = fmaf(hs[d], Wdec[(size_t)d * A_ + a], s);
    ds[a] = s;
  }
  __syncthreads();

  int wv_ = tid >> 6, ln = tid & 63;
  float bA0 = bA[0];
  for (int p = wv_; p < P_; p += 8) {
    const float* ep = encs + (size_t)(b * P_ + p) * A_;
    float s = 0.f;
#pragma unroll
    for (int a = ln; a < A_; a += 64) s += tanhx(ep[a] + ds[a]) * wA[a];
#pragma unroll
    for (int off = 32; off; off >>= 1) s += __shfl_down(s, off);
    if (ln == 0) sc[p] = s + bA0;
  }
  __syncthreads();

  if (tid == 0) {
    float mx = -1e30f;
    for (int p = 0; p < P_; p++) mx = fmaxf(mx, sc[p]);
    float sum = 0.f;
    for (int p = 0; p < P_; p++) { float ex = __expf(sc[p] - mx); sc[p] = ex; sum += ex; }
    inv_s = 1.0f / sum;
  }
  __syncthreads();

  float inv = inv_s;
  for (int e = tid; e < ENC_; e += 512) {
    const float* fp = feat + (size_t)b * P_ * ENC_ + e;
    float s = 0.f;
#pragma unroll
    for (int p = 0; p < P_; p++) s = fmaf(fp[(size_t)p * ENC_], sc[p], s);
    ctx[b * ENC_ + e] = s * inv;
  }
}

// ================= host =================

extern "C" void kernel_launch(void* const* d_in, const int* in_sizes, int n_in,
                              void* d_out, int out_size, void* d_ws, size_t ws_size,
                              hipStream_t stream) {
  const float* features = (const float*)d_in[0];
  const int*   captions = (const int*)d_in[1];
  const float* table    = (const float*)d_in[2];
  const float* Wih  = (const float*)d_in[3];
  const float* bih  = (const float*)d_in[4];
  const float* Whh  = (const float*)d_in[5];
  const float* bhh  = (const float*)d_in[6];
  const float* Winh = (const float*)d_in[7];
  const float* binh = (const float*)d_in[8];
  const float* Winc = (const float*)d_in[9];
  const float* binc = (const float*)d_in[10];
  const float* Wenc = (const float*)d_in[11];
  const float* benc = (const float*)d_in[12];
  const float* Wdec = (const float*)d_in[13];
  const float* bdec = (const float*)d_in[14];
  const float* wA   = (const float*)d_in[15];
  const float* bA   = (const float*)d_in[16];
  const float* Wout = (const float*)d_in[17];
  const float* bout = (const float*)d_in[18];
  float* out = (float*)d_out;

  constexpr size_t F_ENC = (size_t)B_ * P_ * A_;
  constexpr size_t F_C   = (size_t)B_ * D_;
  constexpr size_t F_GP  = (size_t)KSPL * B_ * 4 * D_;   // = WiT size
  constexpr size_t U_WOT = (size_t)V_ * D_;
  constexpr size_t U_WG  = (size_t)(4 * D_) * KX_;
  constexpr size_t U_EMBT = (size_t)B_ * E_;
  constexpr size_t U_CTX = (size_t)B_ * ENC_;
  constexpr size_t U_FEAT = (size_t)B_ * P_ * ENC_;
  constexpr size_t U_WET = (size_t)A_ * ENC_;
  constexpr size_t U_WDT = (size_t)A_ * D_;
  constexpr size_t U_HALL = (size_t)NT_ * B_ * D_;
  constexpr size_t NEED_BYTES =
      (F_ENC + 2 * F_C + F_GP) * 4 +
      (U_WOT + U_WG + U_EMBT + U_CTX + U_FEAT + U_WET + U_HALL) * 2;
  constexpr size_t NEED2 = NEED_BYTES + U_WDT * 2;   // 73,269,248 = R1-proven ws

  if (ws_size >= NEED2) {
    float* ws = (float*)d_ws;
    float* enc_states = ws;
    float* cbuf0  = enc_states + F_ENC;
    float* cbuf1  = cbuf0 + F_C;
    float* gparts = cbuf1 + F_C;                    // WiT (prologue) / gp (loop)
    u16* WoT   = (u16*)(gparts + F_GP);
    u16* Wg    = WoT + U_WOT;
    u16* embt  = Wg + U_WG;
    u16* ctxb  = embt + U_EMBT;
    u16* featb = ctxb + U_CTX;
    u16* WeT   = featb + U_FEAT;
    u16* hall  = WeT + U_WET;
    u16* WdT   = hall + U_HALL;                     // in NEED2 headroom
    u16* WiT   = (u16*)gparts;                      // prologue-only overlay
    u16* mfb   = ctxb;                              // prologue-only overlay
    float* cb[2] = {cbuf0, cbuf1};

    // ---- prologue: 3 launches ----
    k_pro1s<<<PRO1_BLOCKS, 256, 0, stream>>>(features, Winh, Winc, Wenc, Wdec,
                                             Wih, Whh, mfb, featb, WiT, WeT,
                                             WdT, Wg);
    k_trW<<<dim3(V_ / 128, D_ / 256), 256, 0, stream>>>(Wout, WoT);
    k_pro2<<<408, 256, 0, stream>>>(mfb, WiT, binh, binc, hall /*h0*/, cbuf0,
                                    featb, WeT, benc, enc_states);

    // ---- 2-launch step loop (R6 config; h lives in hall) ----
    for (int t = 0; t < NT_; t++) {
      u16* hcur = hall + (size_t)(t > 0 ? t - 1 : 0) * B_ * D_;
      const float* cin = cb[(t > 0 ? (t - 1) : 0) & 1];
      float* cout = cb[t & 1];
      k_att3<<<dim3(64, 2), 512, 0, stream>>>(featb, enc_states, WdT, bdec, wA,
                                              bA, gparts, bih, bhh, cin, cout,
                                              hcur, ctxb, captions, table,
                                              embt, t, t > 0 ? 1 : 0, 1);
      k_gates_bf<<<dim3(32, KSPL), 256, 0, stream>>>(ctxb, embt, hcur, Wg,
                                                     gparts);
    }
    // final reduce -> hall[18]
    k_att3<<<dim3(64, 1), 512, 0, stream>>>(featb, enc_states, WdT, bdec, wA,
                                            bA, gparts, bih, bhh,
                                            cb[(NT_ - 1) & 1], cb[NT_ & 1],
                                            hall + (size_t)(NT_ - 1) * B_ * D_,
                                            ctxb, captions, table, embt, 0,
                                            1, 0);
    // ---- batched logits, windowed hybrid order ----
    k_logits7<<<2560, 256, 0, stream>>>(hall, WoT, bout, out);
  } else {
    // fp32 fallback (R0 path)
    float* ws = (float*)d_ws;
    float* enc_states = ws;
    float* mean_f = enc_states + (size_t)B_ * P_ * A_;
    float* emb    = mean_f + (size_t)B_ * ENC_;
    float* h      = emb + (size_t)B_ * NT_ * E_;
    float* c      = h + (size_t)B_ * D_;
    float* ctx    = c + (size_t)B_ * D_;
    float* gparts = ctx + (size_t)B_ * ENC_;

    k_mean<<<512, 256, 0, stream>>>(features, mean_f);
    k_emb<<<2432, 256, 0, stream>>>(captions, table, emb);
    k_init<<<dim3(2, 64, 2), 256, 0, stream>>>(mean_f, Winh, binh, Winc, binc, h, c);
    k_enc<<<dim3(49, 8), 256, 0, stream>>>(features, Wenc, benc, enc_states);
    k_zero_last<<<2000, 256, 0, stream>>>(out);

    for (int t = 0; t < NT_; t++) {
      k_att<<<64, 512, 0, stream>>>(features, enc_states, Wdec, bdec, wA, bA,
                                    gparts, bih, bhh, h, c, ctx, t > 0 ? 1 : 0, 1);
      if (t > 0)
        k_logits<<<500, 256, 0, stream>>>(h, Wout, bout, out, t - 1);
      k_gates<<<dim3(32, KSPL), 256, 0, stream>>>(ctx, emb, h, Wih, Whh, gparts, t);
    }
    k_att<<<64, 512, 0, stream>>>(features, enc_states, Wdec, bdec, wA, bA,
                                  gparts, bih, bhh, h, c, ctx, 1, 0);
    k_logits<<<500, 256, 0, stream>>>(h, Wout, bout, out, NT_ - 1);
  }
}